// Round 2
// baseline (604.309 us; speedup 1.0000x reference)
//
#include <hip/hip_runtime.h>
#include <hip/hip_bf16.h>
#include <cstdint>
#include <cstddef>

typedef __bf16 bf16;
typedef __bf16 bf16x8 __attribute__((ext_vector_type(8)));
typedef __bf16 bf16x4 __attribute__((ext_vector_type(4)));
typedef float  f32x4  __attribute__((ext_vector_type(4)));

#define MFMA_BF16(a,b,c) __builtin_amdgcn_mfma_f32_16x16x32_bf16((a),(b),(c),0,0,0)

// dims
#define BB 8
#define TT 16
#define PP 256
#define EE 768
#define HH 12
#define HDD 64
#define NQKV 2304
#define MROWS 32768   // B*T*P

__device__ __forceinline__ void gld_lds16(const bf16* g, bf16* l) {
  __builtin_amdgcn_global_load_lds((const __attribute__((address_space(1))) void*)g,
                                   (__attribute__((address_space(3))) void*)l, 16, 0, 0);
}

// ---------------- x fp32 -> bf16 ----------------
__global__ __launch_bounds__(256) void k_cvt_x(const float* __restrict__ x,
                                               bf16* __restrict__ xb) {
  const int64_t i = (int64_t)blockIdx.x * 256 + threadIdx.x;
  const float4* src = (const float4*)x;
  float4 a = src[i * 2];
  float4 b = src[i * 2 + 1];
  bf16x8 o;
  o[0] = (bf16)a.x; o[1] = (bf16)a.y; o[2] = (bf16)a.z; o[3] = (bf16)a.w;
  o[4] = (bf16)b.x; o[5] = (bf16)b.y; o[6] = (bf16)b.z; o[7] = (bf16)b.w;
  *(bf16x8*)(xb + i * 8) = o;
}

// ---------------- weights -> bf16 transposed (B^T layout rows) ----------------
// wt[n][k]: n in [0,768) Wq, [768,1536) Wk, [1536,2304) Wv, [2304,3072) Wo
__global__ __launch_bounds__(256) void k_wt(const float* __restrict__ Wq,
                                            const float* __restrict__ Wk,
                                            const float* __restrict__ Wv,
                                            const float* __restrict__ Wo,
                                            bf16* __restrict__ wt) {
  __shared__ float tile[32][33];
  const int n0 = blockIdx.x * 32;   // 0..3071
  const int k0 = blockIdx.y * 32;   // 0..767
  const float* W;
  int nc;
  if (n0 < 768)        { W = Wq; nc = n0; }
  else if (n0 < 1536)  { W = Wk; nc = n0 - 768; }
  else if (n0 < 2304)  { W = Wv; nc = n0 - 1536; }
  else                 { W = Wo; nc = n0 - 2304; }
  const int tx = threadIdx.x & 31, ty = threadIdx.x >> 5;
  for (int r = ty; r < 32; r += 8)
    tile[r][tx] = W[(int64_t)(k0 + r) * 768 + nc + tx];
  __syncthreads();
  for (int r = ty; r < 32; r += 8)
    wt[(int64_t)(n0 + r) * 768 + k0 + tx] = (bf16)tile[tx][r];
}

// ---------------- QKV GEMM + bias + RoPE + scatter ----------------
// C = xb(32768x768) @ wt[0:2304]^T ; q,k -> (B,T,H,P,HD) with RoPE; v -> (B,T,H,HD,P)
// 3-buffer LDS pipeline, depth-2 prefetch, counted vmcnt(4), ONE raw barrier per K-step.
__global__ __launch_bounds__(256) void k_qkv(const bf16* __restrict__ xb,
                                             const bf16* __restrict__ wt,
                                             const float* __restrict__ bq,
                                             const float* __restrict__ bk,
                                             const float* __restrict__ bv,
                                             bf16* __restrict__ qb,
                                             bf16* __restrict__ kb,
                                             bf16* __restrict__ vt) {
  __shared__ __align__(16) bf16 As[3][128 * 32];
  __shared__ __align__(16) bf16 Bs[3][128 * 32];
  const int tid  = threadIdx.x;
  const int w    = tid >> 6, lane = tid & 63, quad = lane >> 4, l16 = lane & 15;
  const int m0   = blockIdx.x * 128;
  const int n0   = blockIdx.y * 128;
  const int arow = tid >> 2, aseg = (tid & 3) * 8;
  const bf16* Ag = xb + (int64_t)(m0 + arow) * 768 + aseg;
  const bf16* Bg = wt + (int64_t)(n0 + arow) * 768 + aseg;
  const int mb = (w & 1) * 64, nb = (w >> 1) * 64;

  // stage K-tile kt into buffer b: 4 gld_lds (16B/lane) per thread
  auto stage = [&](int kt, int b) {
    bf16* A0 = As[b] + (size_t)w * 512;
    bf16* B0 = Bs[b] + (size_t)w * 512;
    const int k0 = kt * 32;
    gld_lds16(Ag + k0, A0);
    gld_lds16(Ag + 64 * 768 + k0, A0 + 2048);
    gld_lds16(Bg + k0, B0);
    gld_lds16(Bg + 64 * 768 + k0, B0 + 2048);
  };

  f32x4 acc[4][4] = {};
  stage(0, 0);
  stage(1, 1);
  int cur = 0;
  for (int kt = 0; kt < 24; ++kt) {
    // tile kt's 4 loads complete; tile kt+1's 4 may stay in flight (never drain to 0 mid-loop)
    if (kt < 23) { asm volatile("s_waitcnt vmcnt(4)" ::: "memory"); }
    else         { asm volatile("s_waitcnt vmcnt(0)" ::: "memory"); }
    __builtin_amdgcn_s_barrier();
    __builtin_amdgcn_sched_barrier(0);
    if (kt < 22) stage(kt + 2, (kt + 2) % 3);   // WAR safe: last readers drained before this barrier
    const bf16* Ab = As[cur];
    const bf16* Bb = Bs[cur];
    bf16x8 af[4], bfr[4];
#pragma unroll
    for (int i = 0; i < 4; ++i)
      af[i] = *(const bf16x8*)&Ab[(mb + i * 16 + l16) * 32 + quad * 8];
#pragma unroll
    for (int i = 0; i < 4; ++i)
      bfr[i] = *(const bf16x8*)&Bb[(nb + i * 16 + l16) * 32 + quad * 8];
#pragma unroll
    for (int mi = 0; mi < 4; ++mi)
#pragma unroll
      for (int ni = 0; ni < 4; ++ni)
        acc[mi][ni] = MFMA_BF16(af[mi], bfr[ni], acc[mi][ni]);
    cur = (cur == 2) ? 0 : cur + 1;
  }
  // ---- epilogue ----
  const int sec = n0 / 768;            // block-uniform: 0=q 1=k 2=v
  const int nl0 = (n0 % 768) + nb;
  const float* bias_p = (sec == 0) ? bq : (sec == 1) ? bk : bv;
  if (sec == 2) {
#pragma unroll
    for (int ni = 0; ni < 4; ++ni) {
      const int ng = nl0 + ni * 16 + l16;  // 0..767
      const int h = ng >> 6, hd = ng & 63;
      const float bias = bias_p[ng];
#pragma unroll
      for (int mi = 0; mi < 4; ++mi) {
        const int rb = m0 + mb + mi * 16 + quad * 4;
        const int bt = rb >> 8, p = rb & 255;
        bf16x4 pk;
#pragma unroll
        for (int r = 0; r < 4; ++r) pk[r] = (bf16)(acc[mi][ni][r] + bias);
        *(bf16x4*)&vt[((int64_t)(bt * 12 + h) * 64 + hd) * 256 + p] = pk;
      }
    }
  } else {
    bf16* dst = (sec == 0) ? qb : kb;
    const float L2C = 0.83048202372184058696f;  // log2(10000)/16
#pragma unroll
    for (int ni = 0; ni < 4; ++ni) {
      const int ng = nl0 + ni * 16 + l16;
      const int h = ng >> 6, hd = ng & 63;
      const float bias = bias_p[ng];
      const int j = (hd & 31) >> 1;
      const float invf = exp2f(-(float)j * L2C);
      const bool odd = (hd & 1);
      const bool isx = (hd < 32);
#pragma unroll
      for (int mi = 0; mi < 4; ++mi) {
        const int rb = m0 + mb + mi * 16 + quad * 4;
        const int bt = rb >> 8;
        const int pb = rb & 255;
#pragma unroll
        for (int r = 0; r < 4; ++r) {
          const int p = pb + r;
          float v = acc[mi][ni][r] + bias;
          float pv = __shfl_xor(v, 1, 64);  // partner column (n ^ 1), same row
          const int pos = isx ? (p & 15) : (p >> 4);
          float sn, cs;
          __sincosf((float)pos * invf, &sn, &cs);
          float o = odd ? (v * cs + pv * sn) : (v * cs - pv * sn);
          dst[((int64_t)(bt * 12 + h) * 256 + p) * 64 + hd] = (bf16)o;
        }
      }
    }
  }
}

// ---------------- attention: per (b,t,h) block ----------------
// Q,K: (P,HD) row-major per head; V: (HD,P) row-major per head. y overwrites Q.
// Waves are fully independent (per-wave LDS slice, per-wave Q rows): no block barriers,
// only in-wave lgkmcnt fences for the LDS P round-trip. T5 setprio around MFMA clusters.
__global__ __launch_bounds__(256) void k_attn(bf16* qy,
                                              const bf16* __restrict__ kb,
                                              const bf16* __restrict__ vt) {
  __shared__ __align__(16) bf16 plds[4][16 * 264];  // per-wave, stride 264 pads banks
  const int tid = threadIdx.x;
  const int w = tid >> 6, lane = tid & 63, quad = lane >> 4, l16 = lane & 15;
  const int64_t base = (int64_t)blockIdx.x * 16384;  // 256*64
  bf16* Q = qy + base;
  const bf16* K = kb + base;
  const bf16* V = vt + base;
  bf16* pl = plds[w];
  for (int s = 0; s < 4; ++s) {
    const int r0 = w * 64 + s * 16;
    bf16x8 qf0 = *(const bf16x8*)&Q[(r0 + l16) * 64 + quad * 8];
    bf16x8 qf1 = *(const bf16x8*)&Q[(r0 + l16) * 64 + 32 + quad * 8];
    f32x4 sacc[16] = {};
    __builtin_amdgcn_s_setprio(1);
#pragma unroll
    for (int ct = 0; ct < 16; ++ct) {
      bf16x8 kf0 = *(const bf16x8*)&K[(ct * 16 + l16) * 64 + quad * 8];
      bf16x8 kf1 = *(const bf16x8*)&K[(ct * 16 + l16) * 64 + 32 + quad * 8];
      sacc[ct] = MFMA_BF16(qf0, kf0, sacc[ct]);
      sacc[ct] = MFMA_BF16(qf1, kf1, sacc[ct]);
    }
    __builtin_amdgcn_s_setprio(0);
    // softmax over 256 cols; rows live as (quad,reg); cols spread over 16 lanes x 16 tiles
    float mx[4] = {-3e38f, -3e38f, -3e38f, -3e38f};
#pragma unroll
    for (int ct = 0; ct < 16; ++ct)
#pragma unroll
      for (int r = 0; r < 4; ++r) mx[r] = fmaxf(mx[r], sacc[ct][r]);
#pragma unroll
    for (int d = 1; d < 16; d <<= 1)
#pragma unroll
      for (int r = 0; r < 4; ++r) mx[r] = fmaxf(mx[r], __shfl_xor(mx[r], d, 64));
    float sm[4] = {0.f, 0.f, 0.f, 0.f};
#pragma unroll
    for (int ct = 0; ct < 16; ++ct)
#pragma unroll
      for (int r = 0; r < 4; ++r) {
        float e = __expf((sacc[ct][r] - mx[r]) * 0.125f);
        sacc[ct][r] = e;
        sm[r] += e;
      }
#pragma unroll
    for (int d = 1; d < 16; d <<= 1)
#pragma unroll
      for (int r = 0; r < 4; ++r) sm[r] += __shfl_xor(sm[r], d, 64);
    // P: C-layout -> LDS -> A-layout (same-wave cross-lane round-trip)
#pragma unroll
    for (int ct = 0; ct < 16; ++ct)
#pragma unroll
      for (int r = 0; r < 4; ++r)
        pl[(quad * 4 + r) * 264 + ct * 16 + l16] = (bf16)sacc[ct][r];
    asm volatile("s_waitcnt lgkmcnt(0)" ::: "memory");  // in-wave: writes landed before reads
    __builtin_amdgcn_sched_barrier(0);
    f32x4 oacc[4] = {};
    __builtin_amdgcn_s_setprio(1);
#pragma unroll
    for (int kc = 0; kc < 8; ++kc) {
      bf16x8 pf = *(const bf16x8*)&pl[l16 * 264 + kc * 32 + quad * 8];
#pragma unroll
      for (int nt = 0; nt < 4; ++nt) {
        bf16x8 vf = *(const bf16x8*)&V[(nt * 16 + l16) * 256 + kc * 32 + quad * 8];
        oacc[nt] = MFMA_BF16(pf, vf, oacc[nt]);
      }
    }
    __builtin_amdgcn_s_setprio(0);
    float inv[4];
#pragma unroll
    for (int r = 0; r < 4; ++r) inv[r] = 1.0f / sm[r];
#pragma unroll
    for (int nt = 0; nt < 4; ++nt)
#pragma unroll
      for (int r = 0; r < 4; ++r)
        Q[(r0 + quad * 4 + r) * 64 + nt * 16 + l16] = (bf16)(oacc[nt][r] * inv[r]);
    asm volatile("" ::: "memory");  // compiler fence: keep next-s pl writes below this-s pl reads
  }
}

// ---------------- out GEMM: y(b,t,h,p,hd) @ Wo -> d_out fp32 ----------------
// Same 3-buffer counted-vmcnt pipeline as k_qkv.
__global__ __launch_bounds__(256) void k_out(const bf16* __restrict__ yb,
                                             const bf16* __restrict__ wt,
                                             float* __restrict__ out) {
  __shared__ __align__(16) bf16 As[3][128 * 32];
  __shared__ __align__(16) bf16 Bs[3][128 * 32];
  const int tid = threadIdx.x;
  const int w = tid >> 6, lane = tid & 63, quad = lane >> 4, l16 = lane & 15;
  const int m0 = blockIdx.x * 128;
  const int n0 = blockIdx.y * 128;
  const int bt = m0 >> 8, p0 = m0 & 255;
  const int arow = tid >> 2, aseg = (tid & 3) * 8;
  const bf16* Bg = wt + (int64_t)(2304 + n0 + arow) * 768 + aseg;
  const int mb = (w & 1) * 64, nb = (w >> 1) * 64;

  auto stage = [&](int kt, int b) {
    const int h = kt >> 1, hd0 = (kt & 1) * 32;
    const bf16* Ag = yb + ((int64_t)(bt * 12 + h) * 256 + p0 + arow) * 64 + hd0 + aseg;
    bf16* A0 = As[b] + (size_t)w * 512;
    bf16* B0 = Bs[b] + (size_t)w * 512;
    gld_lds16(Ag, A0);
    gld_lds16(Ag + 64 * 64, A0 + 2048);
    gld_lds16(Bg + kt * 32, B0);
    gld_lds16(Bg + 64 * 768 + kt * 32, B0 + 2048);
  };

  f32x4 acc[4][4] = {};
  stage(0, 0);
  stage(1, 1);
  int cur = 0;
  for (int kt = 0; kt < 24; ++kt) {
    if (kt < 23) { asm volatile("s_waitcnt vmcnt(4)" ::: "memory"); }
    else         { asm volatile("s_waitcnt vmcnt(0)" ::: "memory"); }
    __builtin_amdgcn_s_barrier();
    __builtin_amdgcn_sched_barrier(0);
    if (kt < 22) stage(kt + 2, (kt + 2) % 3);
    const bf16* Ab = As[cur];
    const bf16* Bb = Bs[cur];
    bf16x8 af[4], bfr[4];
#pragma unroll
    for (int i = 0; i < 4; ++i)
      af[i] = *(const bf16x8*)&Ab[(mb + i * 16 + l16) * 32 + quad * 8];
#pragma unroll
    for (int i = 0; i < 4; ++i)
      bfr[i] = *(const bf16x8*)&Bb[(nb + i * 16 + l16) * 32 + quad * 8];
#pragma unroll
    for (int mi = 0; mi < 4; ++mi)
#pragma unroll
      for (int ni = 0; ni < 4; ++ni)
        acc[mi][ni] = MFMA_BF16(af[mi], bfr[ni], acc[mi][ni]);
    cur = (cur == 2) ? 0 : cur + 1;
  }
#pragma unroll
  for (int mi = 0; mi < 4; ++mi)
#pragma unroll
    for (int ni = 0; ni < 4; ++ni) {
      const int rg = m0 + mb + mi * 16 + quad * 4;
      const int cg = n0 + nb + ni * 16 + l16;
#pragma unroll
      for (int r = 0; r < 4; ++r)
        out[(int64_t)(rg + r) * 768 + cg] = acc[mi][ni][r];
    }
}

extern "C" void kernel_launch(void* const* d_in, const int* in_sizes, int n_in,
                              void* d_out, int out_size, void* d_ws, size_t ws_size,
                              hipStream_t stream) {
  const float* x  = (const float*)d_in[0];
  const float* Wq = (const float*)d_in[1];
  const float* bq = (const float*)d_in[2];
  const float* Wk = (const float*)d_in[3];
  const float* bk = (const float*)d_in[4];
  const float* Wv = (const float*)d_in[5];
  const float* bv = (const float*)d_in[6];
  const float* Wo = (const float*)d_in[7];
  float* out = (float*)d_out;

  uint8_t* ws = (uint8_t*)d_ws;
  const size_t SZ = (size_t)25165824 * 2;        // one (B,T,H,P,HD) bf16 tensor
  bf16* qy = (bf16*)ws;                          // q, later reused as y
  bf16* kb = (bf16*)(ws + SZ);
  bf16* vt = (bf16*)(ws + 2 * SZ);
  bf16* wt = (bf16*)(ws + 3 * SZ);               // 3072x768 bf16
  bf16* xb = (bf16*)d_out;                       // x-bf16 scratch inside output buffer

  k_cvt_x<<<12288, 256, 0, stream>>>(x, xb);
  k_wt<<<dim3(96, 24), 256, 0, stream>>>(Wq, Wk, Wv, Wo, wt);
  k_qkv<<<dim3(256, 18), 256, 0, stream>>>(xb, wt, bq, bk, bv, qy, kb, vt);
  k_attn<<<1536, 256, 0, stream>>>(qy, kb, vt);
  k_out<<<dim3(256, 6), 256, 0, stream>>>(qy, wt, out);
}

// Round 3
// 557.653 us; speedup vs baseline: 1.0837x; 1.0837x over previous
//
#include <hip/hip_runtime.h>
#include <hip/hip_bf16.h>
#include <cstdint>
#include <cstddef>

typedef __bf16 bf16;
typedef __bf16 bf16x8 __attribute__((ext_vector_type(8)));
typedef __bf16 bf16x4 __attribute__((ext_vector_type(4)));
typedef float  f32x4  __attribute__((ext_vector_type(4)));

#define MFMA_BF16(a,b,c) __builtin_amdgcn_mfma_f32_16x16x32_bf16((a),(b),(c),0,0,0)

// dims
#define BB 8
#define TT 16
#define PP 256
#define EE 768
#define HH 12
#define HDD 64
#define NQKV 2304
#define MROWS 32768   // B*T*P

__device__ __forceinline__ void gld_lds16(const bf16* g, bf16* l) {
  __builtin_amdgcn_global_load_lds((const __attribute__((address_space(1))) void*)g,
                                   (__attribute__((address_space(3))) void*)l, 16, 0, 0);
}

// ---------------- x fp32 -> bf16 ----------------
__global__ __launch_bounds__(256) void k_cvt_x(const float* __restrict__ x,
                                               bf16* __restrict__ xb) {
  const int64_t i = (int64_t)blockIdx.x * 256 + threadIdx.x;
  const float4* src = (const float4*)x;
  float4 a = src[i * 2];
  float4 b = src[i * 2 + 1];
  bf16x8 o;
  o[0] = (bf16)a.x; o[1] = (bf16)a.y; o[2] = (bf16)a.z; o[3] = (bf16)a.w;
  o[4] = (bf16)b.x; o[5] = (bf16)b.y; o[6] = (bf16)b.z; o[7] = (bf16)b.w;
  *(bf16x8*)(xb + i * 8) = o;
}

// ---------------- weights -> bf16 transposed (B^T layout rows) ----------------
// wt[n][k]: n in [0,768) Wq, [768,1536) Wk, [1536,2304) Wv, [2304,3072) Wo
__global__ __launch_bounds__(256) void k_wt(const float* __restrict__ Wq,
                                            const float* __restrict__ Wk,
                                            const float* __restrict__ Wv,
                                            const float* __restrict__ Wo,
                                            bf16* __restrict__ wt) {
  __shared__ float tile[32][33];
  const int n0 = blockIdx.x * 32;   // 0..3071
  const int k0 = blockIdx.y * 32;   // 0..767
  const float* W;
  int nc;
  if (n0 < 768)        { W = Wq; nc = n0; }
  else if (n0 < 1536)  { W = Wk; nc = n0 - 768; }
  else if (n0 < 2304)  { W = Wv; nc = n0 - 1536; }
  else                 { W = Wo; nc = n0 - 2304; }
  const int tx = threadIdx.x & 31, ty = threadIdx.x >> 5;
  for (int r = ty; r < 32; r += 8)
    tile[r][tx] = W[(int64_t)(k0 + r) * 768 + nc + tx];
  __syncthreads();
  for (int r = ty; r < 32; r += 8)
    wt[(int64_t)(n0 + r) * 768 + k0 + tx] = (bf16)tile[tx][r];
}

// ---------------- QKV GEMM + bias + RoPE + scatter ----------------
// C = xb(32768x768) @ wt[0:2304]^T ; q,k -> (B,T,H,P,HD) with RoPE; v -> (B,T,H,HD,P)
// XCD-supertiled block remap: xcd = bid&7 owns a 32-m-block slab, n iterates innermost
// so ~64 in-flight blocks per XCD share one A-tile (L2-hit) and keep B panel (3.5MB)
// L2-resident. Kernel body identical to the verified 2-phase baseline.
__global__ __launch_bounds__(256) void k_qkv(const bf16* __restrict__ xb,
                                             const bf16* __restrict__ wt,
                                             const float* __restrict__ bq,
                                             const float* __restrict__ bk,
                                             const float* __restrict__ bv,
                                             bf16* __restrict__ qb,
                                             bf16* __restrict__ kb,
                                             bf16* __restrict__ vt) {
  __shared__ __align__(16) bf16 As[128 * 32];
  __shared__ __align__(16) bf16 Bs[128 * 32];
  const int tid  = threadIdx.x;
  const int w    = tid >> 6, lane = tid & 63, quad = lane >> 4, l16 = lane & 15;
  // ---- L2-supertiled decode: 4608 blocks = 8 xcd * 32 m * 18 n (n innermost) ----
  const int bid = blockIdx.x;
  const int xcd = bid & 7;
  const int loc = bid >> 3;            // 0..575
  const int m0  = (xcd * 32 + loc / 18) * 128;
  const int n0  = (loc % 18) * 128;
  const int arow = tid >> 2, aseg = (tid & 3) * 8;
  const bf16* Ag = xb + (int64_t)(m0 + arow) * 768 + aseg;
  const bf16* Bg = wt + (int64_t)(n0 + arow) * 768 + aseg;
  bf16* AsW0 = As + (size_t)w * 512;
  bf16* AsW1 = As + 2048 + (size_t)w * 512;
  bf16* BsW0 = Bs + (size_t)w * 512;
  bf16* BsW1 = Bs + 2048 + (size_t)w * 512;
  const int mb = (w & 1) * 64, nb = (w >> 1) * 64;
  f32x4 acc[4][4] = {};
  for (int kt = 0; kt < 24; ++kt) {
    const int k0 = kt * 32;
    gld_lds16(Ag + k0, AsW0);
    gld_lds16(Ag + 64 * 768 + k0, AsW1);
    gld_lds16(Bg + k0, BsW0);
    gld_lds16(Bg + 64 * 768 + k0, BsW1);
    __syncthreads();
    bf16x8 af[4], bfr[4];
#pragma unroll
    for (int i = 0; i < 4; ++i)
      af[i] = *(const bf16x8*)&As[(mb + i * 16 + l16) * 32 + quad * 8];
#pragma unroll
    for (int i = 0; i < 4; ++i)
      bfr[i] = *(const bf16x8*)&Bs[(nb + i * 16 + l16) * 32 + quad * 8];
#pragma unroll
    for (int mi = 0; mi < 4; ++mi)
#pragma unroll
      for (int ni = 0; ni < 4; ++ni)
        acc[mi][ni] = MFMA_BF16(af[mi], bfr[ni], acc[mi][ni]);
    __syncthreads();
  }
  // ---- epilogue ----
  const int sec = n0 / 768;            // block-uniform: 0=q 1=k 2=v
  const int nl0 = (n0 % 768) + nb;
  const float* bias_p = (sec == 0) ? bq : (sec == 1) ? bk : bv;
  if (sec == 2) {
#pragma unroll
    for (int ni = 0; ni < 4; ++ni) {
      const int ng = nl0 + ni * 16 + l16;  // 0..767
      const int h = ng >> 6, hd = ng & 63;
      const float bias = bias_p[ng];
#pragma unroll
      for (int mi = 0; mi < 4; ++mi) {
        const int rb = m0 + mb + mi * 16 + quad * 4;
        const int bt = rb >> 8, p = rb & 255;
        bf16x4 pk;
#pragma unroll
        for (int r = 0; r < 4; ++r) pk[r] = (bf16)(acc[mi][ni][r] + bias);
        *(bf16x4*)&vt[((int64_t)(bt * 12 + h) * 64 + hd) * 256 + p] = pk;
      }
    }
  } else {
    bf16* dst = (sec == 0) ? qb : kb;
    const float L2C = 0.83048202372184058696f;  // log2(10000)/16
#pragma unroll
    for (int ni = 0; ni < 4; ++ni) {
      const int ng = nl0 + ni * 16 + l16;
      const int h = ng >> 6, hd = ng & 63;
      const float bias = bias_p[ng];
      const int j = (hd & 31) >> 1;
      const float invf = exp2f(-(float)j * L2C);
      const bool odd = (hd & 1);
      const bool isx = (hd < 32);
#pragma unroll
      for (int mi = 0; mi < 4; ++mi) {
        const int rb = m0 + mb + mi * 16 + quad * 4;
        const int bt = rb >> 8;
        const int pb = rb & 255;
#pragma unroll
        for (int r = 0; r < 4; ++r) {
          const int p = pb + r;
          float v = acc[mi][ni][r] + bias;
          float pv = __shfl_xor(v, 1, 64);  // partner column (n ^ 1), same row
          const int pos = isx ? (p & 15) : (p >> 4);
          float sn, cs;
          __sincosf((float)pos * invf, &sn, &cs);
          float o = odd ? (v * cs + pv * sn) : (v * cs - pv * sn);
          dst[((int64_t)(bt * 12 + h) * 256 + p) * 64 + hd] = (bf16)o;
        }
      }
    }
  }
}

// ---------------- attention: per (b,t,h) block ----------------
// Q,K: (P,HD) row-major per head; V: (HD,P) row-major per head. y overwrites Q.
__global__ __launch_bounds__(256) void k_attn(bf16* qy,
                                              const bf16* __restrict__ kb,
                                              const bf16* __restrict__ vt) {
  __shared__ __align__(16) bf16 plds[4][16 * 264];  // per-wave, stride 264 pads banks
  const int tid = threadIdx.x;
  const int w = tid >> 6, lane = tid & 63, quad = lane >> 4, l16 = lane & 15;
  const int64_t base = (int64_t)blockIdx.x * 16384;  // 256*64
  bf16* Q = qy + base;
  const bf16* K = kb + base;
  const bf16* V = vt + base;
  bf16* pl = plds[w];
  for (int s = 0; s < 4; ++s) {
    const int r0 = w * 64 + s * 16;
    bf16x8 qf0 = *(const bf16x8*)&Q[(r0 + l16) * 64 + quad * 8];
    bf16x8 qf1 = *(const bf16x8*)&Q[(r0 + l16) * 64 + 32 + quad * 8];
    f32x4 sacc[16] = {};
#pragma unroll
    for (int ct = 0; ct < 16; ++ct) {
      bf16x8 kf0 = *(const bf16x8*)&K[(ct * 16 + l16) * 64 + quad * 8];
      bf16x8 kf1 = *(const bf16x8*)&K[(ct * 16 + l16) * 64 + 32 + quad * 8];
      sacc[ct] = MFMA_BF16(qf0, kf0, sacc[ct]);
      sacc[ct] = MFMA_BF16(qf1, kf1, sacc[ct]);
    }
    // softmax over 256 cols; rows live as (quad,reg); cols spread over 16 lanes x 16 tiles
    float mx[4] = {-3e38f, -3e38f, -3e38f, -3e38f};
#pragma unroll
    for (int ct = 0; ct < 16; ++ct)
#pragma unroll
      for (int r = 0; r < 4; ++r) mx[r] = fmaxf(mx[r], sacc[ct][r]);
#pragma unroll
    for (int d = 1; d < 16; d <<= 1)
#pragma unroll
      for (int r = 0; r < 4; ++r) mx[r] = fmaxf(mx[r], __shfl_xor(mx[r], d, 64));
    float sm[4] = {0.f, 0.f, 0.f, 0.f};
#pragma unroll
    for (int ct = 0; ct < 16; ++ct)
#pragma unroll
      for (int r = 0; r < 4; ++r) {
        float e = __expf((sacc[ct][r] - mx[r]) * 0.125f);
        sacc[ct][r] = e;
        sm[r] += e;
      }
#pragma unroll
    for (int d = 1; d < 16; d <<= 1)
#pragma unroll
      for (int r = 0; r < 4; ++r) sm[r] += __shfl_xor(sm[r], d, 64);
    // P: C-layout -> LDS -> A-layout
#pragma unroll
    for (int ct = 0; ct < 16; ++ct)
#pragma unroll
      for (int r = 0; r < 4; ++r)
        pl[(quad * 4 + r) * 264 + ct * 16 + l16] = (bf16)sacc[ct][r];
    __syncthreads();
    f32x4 oacc[4] = {};
#pragma unroll
    for (int kc = 0; kc < 8; ++kc) {
      bf16x8 pf = *(const bf16x8*)&pl[l16 * 264 + kc * 32 + quad * 8];
#pragma unroll
      for (int nt = 0; nt < 4; ++nt) {
        bf16x8 vf = *(const bf16x8*)&V[(nt * 16 + l16) * 256 + kc * 32 + quad * 8];
        oacc[nt] = MFMA_BF16(pf, vf, oacc[nt]);
      }
    }
    float inv[4];
#pragma unroll
    for (int r = 0; r < 4; ++r) inv[r] = 1.0f / sm[r];
#pragma unroll
    for (int nt = 0; nt < 4; ++nt)
#pragma unroll
      for (int r = 0; r < 4; ++r)
        Q[(r0 + quad * 4 + r) * 64 + nt * 16 + l16] = (bf16)(oacc[nt][r] * inv[r]);
    __syncthreads();
  }
}

// ---------------- out GEMM: y(b,t,h,p,hd) @ Wo -> d_out fp32 ----------------
// Same XCD-supertiled remap: 1536 blocks = 8 xcd * 32 m * 6 n (n innermost).
__global__ __launch_bounds__(256) void k_out(const bf16* __restrict__ yb,
                                             const bf16* __restrict__ wt,
                                             float* __restrict__ out) {
  __shared__ __align__(16) bf16 As[128 * 32];
  __shared__ __align__(16) bf16 Bs[128 * 32];
  const int tid = threadIdx.x;
  const int w = tid >> 6, lane = tid & 63, quad = lane >> 4, l16 = lane & 15;
  const int bid = blockIdx.x;
  const int xcd = bid & 7;
  const int loc = bid >> 3;            // 0..191
  const int m0  = (xcd * 32 + loc / 6) * 128;
  const int n0  = (loc % 6) * 128;
  const int bt = m0 >> 8, p0 = m0 & 255;
  const int arow = tid >> 2, aseg = (tid & 3) * 8;
  const bf16* Bg = wt + (int64_t)(2304 + n0 + arow) * 768 + aseg;
  bf16* AsW0 = As + (size_t)w * 512;
  bf16* AsW1 = As + 2048 + (size_t)w * 512;
  bf16* BsW0 = Bs + (size_t)w * 512;
  bf16* BsW1 = Bs + 2048 + (size_t)w * 512;
  const int mb = (w & 1) * 64, nb = (w >> 1) * 64;
  f32x4 acc[4][4] = {};
  for (int kt = 0; kt < 24; ++kt) {
    const int h = kt >> 1, hd0 = (kt & 1) * 32;
    const bf16* Ag = yb + ((int64_t)(bt * 12 + h) * 256 + p0 + arow) * 64 + hd0 + aseg;
    gld_lds16(Ag, AsW0);
    gld_lds16(Ag + 64 * 64, AsW1);
    gld_lds16(Bg + kt * 32, BsW0);
    gld_lds16(Bg + 64 * 768 + kt * 32, BsW1);
    __syncthreads();
    bf16x8 af[4], bfr[4];
#pragma unroll
    for (int i = 0; i < 4; ++i)
      af[i] = *(const bf16x8*)&As[(mb + i * 16 + l16) * 32 + quad * 8];
#pragma unroll
    for (int i = 0; i < 4; ++i)
      bfr[i] = *(const bf16x8*)&Bs[(nb + i * 16 + l16) * 32 + quad * 8];
#pragma unroll
    for (int mi = 0; mi < 4; ++mi)
#pragma unroll
      for (int ni = 0; ni < 4; ++ni)
        acc[mi][ni] = MFMA_BF16(af[mi], bfr[ni], acc[mi][ni]);
    __syncthreads();
  }
#pragma unroll
  for (int mi = 0; mi < 4; ++mi)
#pragma unroll
    for (int ni = 0; ni < 4; ++ni) {
      const int rg = m0 + mb + mi * 16 + quad * 4;
      const int cg = n0 + nb + ni * 16 + l16;
#pragma unroll
      for (int r = 0; r < 4; ++r)
        out[(int64_t)(rg + r) * 768 + cg] = acc[mi][ni][r];
    }
}

extern "C" void kernel_launch(void* const* d_in, const int* in_sizes, int n_in,
                              void* d_out, int out_size, void* d_ws, size_t ws_size,
                              hipStream_t stream) {
  const float* x  = (const float*)d_in[0];
  const float* Wq = (const float*)d_in[1];
  const float* bq = (const float*)d_in[2];
  const float* Wk = (const float*)d_in[3];
  const float* bk = (const float*)d_in[4];
  const float* Wv = (const float*)d_in[5];
  const float* bv = (const float*)d_in[6];
  const float* Wo = (const float*)d_in[7];
  float* out = (float*)d_out;

  uint8_t* ws = (uint8_t*)d_ws;
  const size_t SZ = (size_t)25165824 * 2;        // one (B,T,H,P,HD) bf16 tensor
  bf16* qy = (bf16*)ws;                          // q, later reused as y
  bf16* kb = (bf16*)(ws + SZ);
  bf16* vt = (bf16*)(ws + 2 * SZ);
  bf16* wt = (bf16*)(ws + 3 * SZ);               // 3072x768 bf16
  bf16* xb = (bf16*)d_out;                       // x-bf16 scratch inside output buffer

  k_cvt_x<<<12288, 256, 0, stream>>>(x, xb);
  k_wt<<<dim3(96, 24), 256, 0, stream>>>(Wq, Wk, Wv, Wo, wt);
  k_qkv<<<4608, 256, 0, stream>>>(xb, wt, bq, bk, bv, qy, kb, vt);
  k_attn<<<1536, 256, 0, stream>>>(qy, kb, vt);
  k_out<<<1536, 256, 0, stream>>>(qy, wt, out);
}

// Round 4
// 526.531 us; speedup vs baseline: 1.1477x; 1.0591x over previous
//
#include <hip/hip_runtime.h>
#include <hip/hip_bf16.h>
#include <cstdint>
#include <cstddef>

typedef __bf16 bf16;
typedef __bf16 bf16x8 __attribute__((ext_vector_type(8)));
typedef __bf16 bf16x4 __attribute__((ext_vector_type(4)));
typedef float  f32x4  __attribute__((ext_vector_type(4)));

#define MFMA_BF16(a,b,c) __builtin_amdgcn_mfma_f32_16x16x32_bf16((a),(b),(c),0,0,0)

// dims
#define BB 8
#define TT 16
#define PP 256
#define EE 768
#define HH 12
#define HDD 64
#define NQKV 2304
#define MROWS 32768   // B*T*P

__device__ __forceinline__ void gld_lds16(const bf16* g, bf16* l) {
  __builtin_amdgcn_global_load_lds((const __attribute__((address_space(1))) void*)g,
                                   (__attribute__((address_space(3))) void*)l, 16, 0, 0);
}

// ---------------- x fp32 -> bf16 ----------------
__global__ __launch_bounds__(256) void k_cvt_x(const float* __restrict__ x,
                                               bf16* __restrict__ xb) {
  const int64_t i = (int64_t)blockIdx.x * 256 + threadIdx.x;
  const float4* src = (const float4*)x;
  float4 a = src[i * 2];
  float4 b = src[i * 2 + 1];
  bf16x8 o;
  o[0] = (bf16)a.x; o[1] = (bf16)a.y; o[2] = (bf16)a.z; o[3] = (bf16)a.w;
  o[4] = (bf16)b.x; o[5] = (bf16)b.y; o[6] = (bf16)b.z; o[7] = (bf16)b.w;
  *(bf16x8*)(xb + i * 8) = o;
}

// ---------------- weights -> bf16 transposed (B^T layout rows) ----------------
// wt[n][k]: n in [0,768) Wq, [768,1536) Wk, [1536,2304) Wv, [2304,3072) Wo
__global__ __launch_bounds__(256) void k_wt(const float* __restrict__ Wq,
                                            const float* __restrict__ Wk,
                                            const float* __restrict__ Wv,
                                            const float* __restrict__ Wo,
                                            bf16* __restrict__ wt) {
  __shared__ float tile[32][33];
  const int n0 = blockIdx.x * 32;   // 0..3071
  const int k0 = blockIdx.y * 32;   // 0..767
  const float* W;
  int nc;
  if (n0 < 768)        { W = Wq; nc = n0; }
  else if (n0 < 1536)  { W = Wk; nc = n0 - 768; }
  else if (n0 < 2304)  { W = Wv; nc = n0 - 1536; }
  else                 { W = Wo; nc = n0 - 2304; }
  const int tx = threadIdx.x & 31, ty = threadIdx.x >> 5;
  for (int r = ty; r < 32; r += 8)
    tile[r][tx] = W[(int64_t)(k0 + r) * 768 + nc + tx];
  __syncthreads();
  for (int r = ty; r < 32; r += 8)
    wt[(int64_t)(n0 + r) * 768 + k0 + tx] = (bf16)tile[tx][r];
}

// ---------------- QKV GEMM + bias + RoPE + scatter ----------------
// 256x256 tile, BK=64, 8 waves (2Mx4N), 128 KiB dynamic LDS double-buffer.
// Stage(t+1) issued BEFORE compute(t): load latency hides under 64 MFMA/wave.
// LDS chunk-XOR swizzle (both sides, via pre-swizzled global source since
// global_load_lds writes linearly): slot(row, c) holds global chunk c^(row&7),
// spreading each ds_read_b128 wave uniformly over the 8 bank-quads.
__global__ __launch_bounds__(512, 2) void k_qkv(const bf16* __restrict__ xb,
                                                const bf16* __restrict__ wt,
                                                const float* __restrict__ bq,
                                                const float* __restrict__ bk,
                                                const float* __restrict__ bv,
                                                bf16* __restrict__ qb,
                                                bf16* __restrict__ kb,
                                                bf16* __restrict__ vt) {
  extern __shared__ char smem_raw[];
  bf16* smem = (bf16*)smem_raw;          // [2][A:16384 | B:16384] elements
  const int tid = threadIdx.x;
  const int w = tid >> 6, lane = tid & 63, quad = lane >> 4, l16 = lane & 15;
  const int wr = w >> 2, wc = w & 3;     // 2 x 4 wave grid
  const int kap = l16 & 7;               // per-thread chunk XOR key
  // ---- L2-supertiled decode: 1152 blocks = 8 xcd * 16 m * 9 n (n innermost) ----
  const int bid = blockIdx.x;
  const int xcd = bid & 7;
  const int loc = bid >> 3;              // 0..143
  const int m0  = (xcd * 16 + loc / 9) * 256;
  const int n0  = (loc % 9) * 256;
  // staging: per gld_lds a wave writes 8 LDS rows; lane supplies row lane>>3,
  // chunk lane&7, fetched from global chunk (lane&7)^((lane>>3)&7)  (involution)
  const int srow = w * 8 + (lane >> 3);
  const int cgo  = ((lane & 7) ^ ((lane >> 3) & 7)) * 8;
  const bf16* Ag = xb + (int64_t)(m0 + srow) * 768 + cgo;
  const bf16* Bg = wt + (int64_t)(n0 + srow) * 768 + cgo;

  auto stage = [&](int kt, int p) {
    bf16* LA = smem + p * 32768 + w * 512;
    bf16* LB = LA + 16384;
    const bf16* GA = Ag + kt * 64;
    const bf16* GB = Bg + kt * 64;
#pragma unroll
    for (int rd = 0; rd < 4; ++rd) {
      gld_lds16(GA + rd * 49152, LA + rd * 4096);   // 64 rows per round
      gld_lds16(GB + rd * 49152, LB + rd * 4096);
    }
  };

  f32x4 acc[8][4] = {};
  stage(0, 0);
  __syncthreads();
  for (int t = 0; t < 12; ++t) {
    if (t < 11) stage(t + 1, (t + 1) & 1);      // overlaps this tile's compute
    __builtin_amdgcn_sched_barrier(0);          // keep stage issue early
    const bf16* A = smem + (t & 1) * 32768;
    const bf16* B = A + 16384;
    bf16x8 bfr[4][2];
#pragma unroll
    for (int ni = 0; ni < 4; ++ni)
#pragma unroll
      for (int kk = 0; kk < 2; ++kk)
        bfr[ni][kk] = *(const bf16x8*)&B[(wc * 64 + ni * 16 + l16) * 64 +
                                         (((kk * 4 + quad) ^ kap) * 8)];
#pragma unroll
    for (int mh = 0; mh < 2; ++mh) {
      bf16x8 afr[4][2];
#pragma unroll
      for (int mi = 0; mi < 4; ++mi)
#pragma unroll
        for (int kk = 0; kk < 2; ++kk)
          afr[mi][kk] = *(const bf16x8*)&A[(wr * 128 + mh * 64 + mi * 16 + l16) * 64 +
                                           (((kk * 4 + quad) ^ kap) * 8)];
      __builtin_amdgcn_s_setprio(1);
#pragma unroll
      for (int mi = 0; mi < 4; ++mi)
#pragma unroll
        for (int ni = 0; ni < 4; ++ni)
#pragma unroll
          for (int kk = 0; kk < 2; ++kk)
            acc[mh * 4 + mi][ni] = MFMA_BF16(afr[mi][kk], bfr[ni][kk], acc[mh * 4 + mi][ni]);
      __builtin_amdgcn_s_setprio(0);
    }
    __syncthreads();   // drains vmcnt: stage(t+1) had the whole compute to land
  }
  // ---- epilogue ----
  const int sec = n0 / 768;            // block-uniform: 0=q 1=k 2=v
  const float* bias_p = (sec == 0) ? bq : (sec == 1) ? bk : bv;
  if (sec == 2) {
#pragma unroll
    for (int ni = 0; ni < 4; ++ni) {
      const int ng = (n0 % 768) + wc * 64 + ni * 16 + l16;  // 0..767
      const int h = ng >> 6, hd = ng & 63;
      const float bias = bias_p[ng];
#pragma unroll
      for (int mi = 0; mi < 8; ++mi) {
        const int rb = m0 + wr * 128 + mi * 16 + quad * 4;
        const int bt = rb >> 8, p = rb & 255;
        bf16x4 pk;
#pragma unroll
        for (int r = 0; r < 4; ++r) pk[r] = (bf16)(acc[mi][ni][r] + bias);
        *(bf16x4*)&vt[((int64_t)(bt * 12 + h) * 64 + hd) * 256 + p] = pk;
      }
    }
  } else {
    bf16* dst = (sec == 0) ? qb : kb;
    const float L2C = 0.83048202372184058696f;  // log2(10000)/16
#pragma unroll
    for (int ni = 0; ni < 4; ++ni) {
      const int ng = (n0 % 768) + wc * 64 + ni * 16 + l16;
      const int h = ng >> 6, hd = ng & 63;
      const float bias = bias_p[ng];
      const int j = (hd & 31) >> 1;
      const float invf = exp2f(-(float)j * L2C);
      const bool odd = (hd & 1);
      const bool isx = (hd < 32);
#pragma unroll
      for (int mi = 0; mi < 8; ++mi) {
        const int rb = m0 + wr * 128 + mi * 16 + quad * 4;
        const int bt = rb >> 8;
        const int pb = rb & 255;
#pragma unroll
        for (int r = 0; r < 4; ++r) {
          const int p = pb + r;
          float v = acc[mi][ni][r] + bias;
          float pv = __shfl_xor(v, 1, 64);  // partner column (n ^ 1), same row
          const int pos = isx ? (p & 15) : (p >> 4);
          float sn, cs;
          __sincosf((float)pos * invf, &sn, &cs);
          float o = odd ? (v * cs + pv * sn) : (v * cs - pv * sn);
          dst[((int64_t)(bt * 12 + h) * 256 + p) * 64 + hd] = (bf16)o;
        }
      }
    }
  }
}

// ---------------- attention: per (b,t,h) block ----------------
// Q,K: (P,HD) row-major per head; V: (HD,P) row-major per head. y overwrites Q.
__global__ __launch_bounds__(256) void k_attn(bf16* qy,
                                              const bf16* __restrict__ kb,
                                              const bf16* __restrict__ vt) {
  __shared__ __align__(16) bf16 plds[4][16 * 264];  // per-wave, stride 264 pads banks
  const int tid = threadIdx.x;
  const int w = tid >> 6, lane = tid & 63, quad = lane >> 4, l16 = lane & 15;
  const int64_t base = (int64_t)blockIdx.x * 16384;  // 256*64
  bf16* Q = qy + base;
  const bf16* K = kb + base;
  const bf16* V = vt + base;
  bf16* pl = plds[w];
  for (int s = 0; s < 4; ++s) {
    const int r0 = w * 64 + s * 16;
    bf16x8 qf0 = *(const bf16x8*)&Q[(r0 + l16) * 64 + quad * 8];
    bf16x8 qf1 = *(const bf16x8*)&Q[(r0 + l16) * 64 + 32 + quad * 8];
    f32x4 sacc[16] = {};
#pragma unroll
    for (int ct = 0; ct < 16; ++ct) {
      bf16x8 kf0 = *(const bf16x8*)&K[(ct * 16 + l16) * 64 + quad * 8];
      bf16x8 kf1 = *(const bf16x8*)&K[(ct * 16 + l16) * 64 + 32 + quad * 8];
      sacc[ct] = MFMA_BF16(qf0, kf0, sacc[ct]);
      sacc[ct] = MFMA_BF16(qf1, kf1, sacc[ct]);
    }
    // softmax over 256 cols; rows live as (quad,reg); cols spread over 16 lanes x 16 tiles
    float mx[4] = {-3e38f, -3e38f, -3e38f, -3e38f};
#pragma unroll
    for (int ct = 0; ct < 16; ++ct)
#pragma unroll
      for (int r = 0; r < 4; ++r) mx[r] = fmaxf(mx[r], sacc[ct][r]);
#pragma unroll
    for (int d = 1; d < 16; d <<= 1)
#pragma unroll
      for (int r = 0; r < 4; ++r) mx[r] = fmaxf(mx[r], __shfl_xor(mx[r], d, 64));
    float sm[4] = {0.f, 0.f, 0.f, 0.f};
#pragma unroll
    for (int ct = 0; ct < 16; ++ct)
#pragma unroll
      for (int r = 0; r < 4; ++r) {
        float e = __expf((sacc[ct][r] - mx[r]) * 0.125f);
        sacc[ct][r] = e;
        sm[r] += e;
      }
#pragma unroll
    for (int d = 1; d < 16; d <<= 1)
#pragma unroll
      for (int r = 0; r < 4; ++r) sm[r] += __shfl_xor(sm[r], d, 64);
    // P: C-layout -> LDS -> A-layout
#pragma unroll
    for (int ct = 0; ct < 16; ++ct)
#pragma unroll
      for (int r = 0; r < 4; ++r)
        pl[(quad * 4 + r) * 264 + ct * 16 + l16] = (bf16)sacc[ct][r];
    __syncthreads();
    f32x4 oacc[4] = {};
#pragma unroll
    for (int kc = 0; kc < 8; ++kc) {
      bf16x8 pf = *(const bf16x8*)&pl[l16 * 264 + kc * 32 + quad * 8];
#pragma unroll
      for (int nt = 0; nt < 4; ++nt) {
        bf16x8 vf = *(const bf16x8*)&V[(nt * 16 + l16) * 256 + kc * 32 + quad * 8];
        oacc[nt] = MFMA_BF16(pf, vf, oacc[nt]);
      }
    }
    float inv[4];
#pragma unroll
    for (int r = 0; r < 4; ++r) inv[r] = 1.0f / sm[r];
#pragma unroll
    for (int nt = 0; nt < 4; ++nt)
#pragma unroll
      for (int r = 0; r < 4; ++r)
        Q[(r0 + quad * 4 + r) * 64 + nt * 16 + l16] = (bf16)(oacc[nt][r] * inv[r]);
    __syncthreads();
  }
}

// ---------------- out GEMM: y(b,t,h,p,hd) @ Wo -> d_out fp32 ----------------
// XCD-supertiled remap: 1536 blocks = 8 xcd * 32 m * 6 n (n innermost).
__global__ __launch_bounds__(256) void k_out(const bf16* __restrict__ yb,
                                             const bf16* __restrict__ wt,
                                             float* __restrict__ out) {
  __shared__ __align__(16) bf16 As[128 * 32];
  __shared__ __align__(16) bf16 Bs[128 * 32];
  const int tid = threadIdx.x;
  const int w = tid >> 6, lane = tid & 63, quad = lane >> 4, l16 = lane & 15;
  const int bid = blockIdx.x;
  const int xcd = bid & 7;
  const int loc = bid >> 3;            // 0..191
  const int m0  = (xcd * 32 + loc / 6) * 128;
  const int n0  = (loc % 6) * 128;
  const int bt = m0 >> 8, p0 = m0 & 255;
  const int arow = tid >> 2, aseg = (tid & 3) * 8;
  const bf16* Bg = wt + (int64_t)(2304 + n0 + arow) * 768 + aseg;
  bf16* AsW0 = As + (size_t)w * 512;
  bf16* AsW1 = As + 2048 + (size_t)w * 512;
  bf16* BsW0 = Bs + (size_t)w * 512;
  bf16* BsW1 = Bs + 2048 + (size_t)w * 512;
  const int mb = (w & 1) * 64, nb = (w >> 1) * 64;
  f32x4 acc[4][4] = {};
  for (int kt = 0; kt < 24; ++kt) {
    const int h = kt >> 1, hd0 = (kt & 1) * 32;
    const bf16* Ag = yb + ((int64_t)(bt * 12 + h) * 256 + p0 + arow) * 64 + hd0 + aseg;
    gld_lds16(Ag, AsW0);
    gld_lds16(Ag + 64 * 64, AsW1);
    gld_lds16(Bg + kt * 32, BsW0);
    gld_lds16(Bg + 64 * 768 + kt * 32, BsW1);
    __syncthreads();
    bf16x8 af[4], bfr[4];
#pragma unroll
    for (int i = 0; i < 4; ++i)
      af[i] = *(const bf16x8*)&As[(mb + i * 16 + l16) * 32 + quad * 8];
#pragma unroll
    for (int i = 0; i < 4; ++i)
      bfr[i] = *(const bf16x8*)&Bs[(nb + i * 16 + l16) * 32 + quad * 8];
#pragma unroll
    for (int mi = 0; mi < 4; ++mi)
#pragma unroll
      for (int ni = 0; ni < 4; ++ni)
        acc[mi][ni] = MFMA_BF16(af[mi], bfr[ni], acc[mi][ni]);
    __syncthreads();
  }
#pragma unroll
  for (int mi = 0; mi < 4; ++mi)
#pragma unroll
    for (int ni = 0; ni < 4; ++ni) {
      const int rg = m0 + mb + mi * 16 + quad * 4;
      const int cg = n0 + nb + ni * 16 + l16;
#pragma unroll
      for (int r = 0; r < 4; ++r)
        out[(int64_t)(rg + r) * 768 + cg] = acc[mi][ni][r];
    }
}

extern "C" void kernel_launch(void* const* d_in, const int* in_sizes, int n_in,
                              void* d_out, int out_size, void* d_ws, size_t ws_size,
                              hipStream_t stream) {
  const float* x  = (const float*)d_in[0];
  const float* Wq = (const float*)d_in[1];
  const float* bq = (const float*)d_in[2];
  const float* Wk = (const float*)d_in[3];
  const float* bk = (const float*)d_in[4];
  const float* Wv = (const float*)d_in[5];
  const float* bv = (const float*)d_in[6];
  const float* Wo = (const float*)d_in[7];
  float* out = (float*)d_out;

  uint8_t* ws = (uint8_t*)d_ws;
  const size_t SZ = (size_t)25165824 * 2;        // one (B,T,H,P,HD) bf16 tensor
  bf16* qy = (bf16*)ws;                          // q, later reused as y
  bf16* kb = (bf16*)(ws + SZ);
  bf16* vt = (bf16*)(ws + 2 * SZ);
  bf16* wt = (bf16*)(ws + 3 * SZ);               // 3072x768 bf16
  bf16* xb = (bf16*)d_out;                       // x-bf16 scratch inside output buffer

  static int attr_set = 0;
  if (!attr_set) {
    (void)hipFuncSetAttribute((const void*)k_qkv,
                              hipFuncAttributeMaxDynamicSharedMemorySize, 131072);
    attr_set = 1;
  }

  k_cvt_x<<<12288, 256, 0, stream>>>(x, xb);
  k_wt<<<dim3(96, 24), 256, 0, stream>>>(Wq, Wk, Wv, Wo, wt);
  k_qkv<<<1152, 512, 131072, stream>>>(xb, wt, bq, bk, bv, qy, kb, vt);
  k_attn<<<1536, 256, 0, stream>>>(qy, kb, vt);
  k_out<<<1536, 256, 0, stream>>>(qy, wt, out);
}